// Round 8
// baseline (8432.340 us; speedup 1.0000x reference)
//
#include <hip/hip_runtime.h>
#include <hip/hip_bf16.h>
#include <hip/hip_cooperative_groups.h>

namespace cg = cooperative_groups;

#define NB 256
#define TT 128
#define DD 1024
#define HH 1024
#define FH 4096
#define KTOT 3072

typedef __attribute__((ext_vector_type(4))) float f32x4;
typedef __attribute__((ext_vector_type(8))) short short8;
typedef __attribute__((ext_vector_type(4))) unsigned u32x4;

__device__ __forceinline__ unsigned short f2bf(float f) {
    union { float f; unsigned u; } v; v.f = f;
    unsigned u = v.u;
    u += 0x7FFFu + ((u >> 16) & 1u);   // RNE
    return (unsigned short)(u >> 16);
}
__device__ __forceinline__ float bf2f(unsigned short u) {
    union { unsigned u; float f; } v; v.u = ((unsigned)u) << 16; return v.f;
}
__device__ __forceinline__ float sigm(float v) { return 1.f / (1.f + __expf(-v)); }
__device__ __forceinline__ float tanhf_(float v) { return 1.f - 2.f / (__expf(2.f * v) + 1.f); }

__device__ __forceinline__ void bmap(int bid, int& m0, int& j0) {
    int xx = bid & 7, yy = (bid >> 3) & 7, mt = bid >> 6;
    m0 = mt * 64;
    j0 = (xx * 8 + yy) * 16;           // XCD-aligned j tiles
}

__device__ __forceinline__ short8 pack8(float4 v0, float4 v1) {
    short8 r;
    r[0] = (short)f2bf(v0.x); r[1] = (short)f2bf(v0.y);
    r[2] = (short)f2bf(v0.z); r[3] = (short)f2bf(v0.w);
    r[4] = (short)f2bf(v1.x); r[5] = (short)f2bf(v1.y);
    r[6] = (short)f2bf(v1.z); r[7] = (short)f2bf(v1.w);
    return r;
}

// ---------------------------------------------------------------------------
// Wt[c][k] bf16: c = gate*1024+j (4096), k = concat(x, h, attn-weight rows)
// ---------------------------------------------------------------------------
__global__ __launch_bounds__(256) void wt_prep(const float* __restrict__ Wx,
                                               const float* __restrict__ Wh,
                                               const float* __restrict__ Wattn,
                                               unsigned short* __restrict__ Wt) {
    __shared__ unsigned short tile[64][65];
    int k0 = blockIdx.x * 64;   // 48
    int c0 = blockIdx.y * 64;   // 64
    const float* src; int kl0;
    if (k0 < 1024)      { src = Wx;    kl0 = k0; }
    else if (k0 < 2048) { src = Wh;    kl0 = k0 - 1024; }
    else                { src = Wattn; kl0 = k0 - 2048; }
    int tid = threadIdx.x;
    int r = tid >> 2;
    int ch = (tid & 3) << 4;
    const float* p = src + (size_t)(kl0 + r) * FH + c0 + ch;
#pragma unroll
    for (int i = 0; i < 16; i += 4) {
        float4 v = *reinterpret_cast<const float4*>(p + i);
        tile[r][ch + i + 0] = f2bf(v.x);
        tile[r][ch + i + 1] = f2bf(v.y);
        tile[r][ch + i + 2] = f2bf(v.z);
        tile[r][ch + i + 3] = f2bf(v.w);
    }
    __syncthreads();
    alignas(16) unsigned short vals[16];
#pragma unroll
    for (int i = 0; i < 16; ++i) vals[i] = tile[ch + i][r];
    unsigned short* q = Wt + (size_t)(c0 + r) * KTOT + k0 + ch;
    *reinterpret_cast<uint4*>(q)     = *reinterpret_cast<uint4*>(&vals[0]);
    *reinterpret_cast<uint4*>(q + 8) = *reinterpret_cast<uint4*>(&vals[8]);
}

__global__ __launch_bounds__(256) void zero_buf(float* __restrict__ p, int n) {
    int i = blockIdx.x * 256 + threadIdx.x;
    if (i < n) p[i] = 0.f;
}

// x (fp32) -> xbf (bf16)
__global__ __launch_bounds__(256) void xconv(const float* __restrict__ x,
                                             unsigned short* __restrict__ xbf) {
    size_t i = ((size_t)blockIdx.x * 256 + threadIdx.x) * 8;
    float4 v0 = *reinterpret_cast<const float4*>(x + i);
    float4 v1 = *reinterpret_cast<const float4*>(x + i + 4);
    short8 p = pack8(v0, v1);
    *reinterpret_cast<short8*>(xbf + i) = p;
}

// AfT[n][l][h] = bf16(A[n][h][l])
__global__ __launch_bounds__(256) void afT_prep(const float* __restrict__ A,
                                                unsigned short* __restrict__ AfT) {
    int n = blockIdx.x;
#pragma unroll
    for (int pass = 0; pass < 4; ++pass) {
        int hh = pass * 256 + threadIdx.x;
        const float4* p = reinterpret_cast<const float4*>(A + ((size_t)n * HH + hh) * 16);
        float4 a0 = p[0], a1 = p[1], a2 = p[2], a3 = p[3];
        float av[16] = {a0.x,a0.y,a0.z,a0.w, a1.x,a1.y,a1.z,a1.w,
                        a2.x,a2.y,a2.z,a2.w, a3.x,a3.y,a3.z,a3.w};
#pragma unroll
        for (int l = 0; l < 16; ++l)
            AfT[((size_t)n * 16 + l) * HH + hh] = f2bf(av[l]);
    }
}

// ---------------------------------------------------------------------------
// G[n][c][l] = sum_h Af[n][h][l] * Wattn[h][c]   (one 4096x4096x1024 GEMM)
// ---------------------------------------------------------------------------
__global__ __launch_bounds__(256) void g_gemm(const unsigned short* __restrict__ AfT,
                                              const unsigned short* __restrict__ Wt,
                                              unsigned short* __restrict__ G) {
    int mt = blockIdx.y;
    int ct = blockIdx.x;
    int tid = threadIdx.x;
    int w = tid >> 6, lane = tid & 63;
    int wm = w >> 1, wn = w & 1;
    int cw = lane & 15, k8 = (lane >> 4) << 3;

    const unsigned short* ap[4];
    const unsigned short* bp[4];
#pragma unroll
    for (int mf = 0; mf < 4; ++mf)
        ap[mf] = AfT + (size_t)(mt * 128 + wm * 64 + mf * 16 + cw) * HH + k8;
#pragma unroll
    for (int fn = 0; fn < 4; ++fn)
        bp[fn] = Wt + (size_t)(ct * 128 + wn * 64 + fn * 16 + cw) * KTOT + 2048 + k8;

    f32x4 acc[4][4];
#pragma unroll
    for (int mf = 0; mf < 4; ++mf)
#pragma unroll
        for (int fn = 0; fn < 4; ++fn)
#pragma unroll
            for (int e = 0; e < 4; ++e) acc[mf][fn][e] = 0.f;

#pragma unroll 4
    for (int ch = 0; ch < 32; ++ch) {
        short8 a[4], b[4];
#pragma unroll
        for (int i = 0; i < 4; ++i)
            a[i] = *reinterpret_cast<const short8*>(ap[i] + ch * 32);
#pragma unroll
        for (int i = 0; i < 4; ++i)
            b[i] = *reinterpret_cast<const short8*>(bp[i] + ch * 32);
#pragma unroll
        for (int mf = 0; mf < 4; ++mf)
#pragma unroll
            for (int fn = 0; fn < 4; ++fn)
                acc[mf][fn] = __builtin_amdgcn_mfma_f32_16x16x32_bf16(
                    a[mf], b[fn], acc[mf][fn], 0, 0, 0);
    }

    int l0 = (lane >> 4) << 2;
#pragma unroll
    for (int mf = 0; mf < 4; ++mf) {
        int n = mt * 8 + wm * 4 + mf;
#pragma unroll
        for (int fn = 0; fn < 4; ++fn) {
            int cc = ct * 128 + wn * 64 + fn * 16 + cw;
            unsigned lo = (unsigned)f2bf(acc[mf][fn][0]) | ((unsigned)f2bf(acc[mf][fn][1]) << 16);
            unsigned hi = (unsigned)f2bf(acc[mf][fn][2]) | ((unsigned)f2bf(acc[mf][fn][3]) << 16);
            uint2 val; val.x = lo; val.y = hi;
            *reinterpret_cast<uint2*>(G + ((size_t)n * FH + cc) * 16 + l0) = val;
        }
    }
}

// ---------------------------------------------------------------------------
// init: h0 = c0 = mean(Af[n,h,:]); h0 bf16; logits(h0) -> lg0
// ---------------------------------------------------------------------------
__global__ __launch_bounds__(512) void init_kernel(const float* __restrict__ A,
                                                   float* __restrict__ c,
                                                   unsigned short* __restrict__ h0,
                                                   float* __restrict__ lg0) {
    int m0, j0; bmap(blockIdx.x, m0, j0);
    int tid = threadIdx.x;
    int r = tid >> 3, j2 = (tid & 7) * 2;
    int n = m0 + r;
    float lg[16];
#pragma unroll
    for (int l = 0; l < 16; ++l) lg[l] = 0.f;
#pragma unroll
    for (int e = 0; e < 2; ++e) {
        int j = j0 + j2 + e;
        const float4* p = reinterpret_cast<const float4*>(A + ((size_t)n * HH + j) * 16);
        float4 a0 = p[0], a1 = p[1], a2 = p[2], a3 = p[3];
        float av[16] = {a0.x,a0.y,a0.z,a0.w, a1.x,a1.y,a1.z,a1.w,
                        a2.x,a2.y,a2.z,a2.w, a3.x,a3.y,a3.z,a3.w};
        float s = 0.f;
#pragma unroll
        for (int l = 0; l < 16; ++l) s += av[l];
        float m = s * 0.0625f;
        c[(size_t)n * HH + j] = m;
        h0[(size_t)n * HH + j] = f2bf(m);
#pragma unroll
        for (int l = 0; l < 16; ++l) lg[l] += m * av[l];
    }
#pragma unroll
    for (int l = 0; l < 16; ++l) {
        lg[l] += __shfl_xor(lg[l], 1);
        lg[l] += __shfl_xor(lg[l], 2);
        lg[l] += __shfl_xor(lg[l], 4);
    }
    int l0 = (tid & 7) * 2;
    atomicAdd(&lg0[(size_t)n * 16 + l0],     lg[l0]);
    atomicAdd(&lg0[(size_t)n * 16 + l0 + 1], lg[l0 + 1]);
}

// ---------------------------------------------------------------------------
// Persistent cooperative kernel: the whole T=128 recurrence.
// Grid 256 blocks x 1024 thr. Block = 64 rows x (4 gates x 16 j).
// 16 waves = 2m x 2n x 4k; wave 32r x 32c, K-quarter 512 (0,1 = x; 2,3 = h).
// Per step: GEMM -> LDS k-reduce -> epilogue (softmax + w.G + LSTM + out)
// -> AfT-based logit partials -> grid.sync().
// G is read with NORMAL cached loads: 33.5 MB, L3-resident across 128 steps.
// ---------------------------------------------------------------------------
template<bool XBF>
__global__ __launch_bounds__(1024)
void lstm_persist(const float* __restrict__ x, const unsigned short* __restrict__ xbf,
                  unsigned short* __restrict__ hbuf,
                  const unsigned short* __restrict__ Wt,
                  const unsigned short* __restrict__ G,
                  const unsigned short* __restrict__ AfT,
                  const float* __restrict__ bb,
                  float* __restrict__ lg,
                  float* __restrict__ c,
                  float* __restrict__ out) {
    cg::grid_group grid = cg::this_grid();
    __shared__ float red[2][64][68];     // k-partial reduce, [pair][col][row]
    __shared__ float hn_s[64][16];       // new h tile for logit partials

    int m0, j0; bmap(blockIdx.x, m0, j0);
    const int tid = threadIdx.x;
    const int w = tid >> 6, lane = tid & 63;
    const int wk = w & 3, wn = (w >> 2) & 1, wm = w >> 3;
    const int cw = lane & 15, k8 = (lane >> 4) << 3;

    // hoisted B pointers (t-invariant)
    const unsigned short* bp0;
    const unsigned short* bp1;
    {
        const int kbase = (wk < 2) ? wk * 512 : 1024 + (wk - 2) * 512;
        int col0 = wn * 32 + cw;
        int col1 = wn * 32 + 16 + cw;
        bp0 = Wt + (size_t)((col0 >> 4) * 1024 + j0 + (col0 & 15)) * KTOT + kbase + k8;
        bp1 = Wt + (size_t)((col1 >> 4) * 1024 + j0 + (col1 & 15)) * KTOT + kbase + k8;
    }
    const int arow0 = m0 + wm * 32 + cw;
    const int arow1 = arow0 + 16;
    const size_t xoff0 = (size_t)arow0 * TT * DD + (size_t)wk * 512 + k8;        // wk<2
    const size_t xoff1 = (size_t)arow1 * TT * DD + (size_t)wk * 512 + k8;
    const size_t hoff0 = (size_t)arow0 * HH + (size_t)(wk - 2) * 512 + k8;       // wk>=2
    const size_t hoff1 = (size_t)arow1 * HH + (size_t)(wk - 2) * 512 + k8;

    // epilogue indices (t-invariant)
    const int er = tid >> 4, ej = tid & 15;
    const int en = m0 + er;
    const int ejj = j0 + ej;
    const bool zeroer = ((blockIdx.x & 63) == 0);
    const float bias[4] = { bb[0 * HH + ejj], bb[1 * HH + ejj],
                            bb[2 * HH + ejj], bb[3 * HH + ejj] };
    const unsigned short* afp = AfT + ((size_t)en * 16 + ej) * HH + j0;
    const u32x4* gbase = reinterpret_cast<const u32x4*>(G + ((size_t)en * FH + ejj) * 16);

    for (int t = 0; t < TT; ++t) {
        const unsigned short* hprev = hbuf + (size_t)(t & 1) * (NB * HH);
        unsigned short* hnext       = hbuf + (size_t)((t & 1) ^ 1) * (NB * HH);
        const float* lgcur = lg + (size_t)(t % 3) * (NB * 16);
        float* lgnext      = lg + (size_t)((t + 1) % 3) * (NB * 16);
        float* lgz         = lg + (size_t)((t + 2) % 3) * (NB * 16);

        f32x4 acc[2][2];
#pragma unroll
        for (int mf = 0; mf < 2; ++mf)
#pragma unroll
            for (int fn = 0; fn < 2; ++fn)
#pragma unroll
                for (int e = 0; e < 4; ++e) acc[mf][fn][e] = 0.f;

        if (wk < 2) {                  // x region
            if (XBF) {
                const unsigned short* a0p = xbf + xoff0 + (size_t)t * DD;
                const unsigned short* a1p = xbf + xoff1 + (size_t)t * DD;
#pragma unroll 4
                for (int ch = 0; ch < 16; ++ch) {
                    short8 a0 = *reinterpret_cast<const short8*>(a0p + ch * 32);
                    short8 a1 = *reinterpret_cast<const short8*>(a1p + ch * 32);
                    short8 b0 = *reinterpret_cast<const short8*>(bp0 + ch * 32);
                    short8 b1 = *reinterpret_cast<const short8*>(bp1 + ch * 32);
                    acc[0][0] = __builtin_amdgcn_mfma_f32_16x16x32_bf16(a0, b0, acc[0][0], 0, 0, 0);
                    acc[0][1] = __builtin_amdgcn_mfma_f32_16x16x32_bf16(a0, b1, acc[0][1], 0, 0, 0);
                    acc[1][0] = __builtin_amdgcn_mfma_f32_16x16x32_bf16(a1, b0, acc[1][0], 0, 0, 0);
                    acc[1][1] = __builtin_amdgcn_mfma_f32_16x16x32_bf16(a1, b1, acc[1][1], 0, 0, 0);
                }
            } else {
                const float* a0p = x + xoff0 + (size_t)t * DD;
                const float* a1p = x + xoff1 + (size_t)t * DD;
#pragma unroll 2
                for (int ch = 0; ch < 16; ++ch) {
                    float4 u0 = *reinterpret_cast<const float4*>(a0p + ch * 32);
                    float4 u1 = *reinterpret_cast<const float4*>(a0p + ch * 32 + 4);
                    float4 v0 = *reinterpret_cast<const float4*>(a1p + ch * 32);
                    float4 v1 = *reinterpret_cast<const float4*>(a1p + ch * 32 + 4);
                    short8 a0 = pack8(u0, u1);
                    short8 a1 = pack8(v0, v1);
                    short8 b0 = *reinterpret_cast<const short8*>(bp0 + ch * 32);
                    short8 b1 = *reinterpret_cast<const short8*>(bp1 + ch * 32);
                    acc[0][0] = __builtin_amdgcn_mfma_f32_16x16x32_bf16(a0, b0, acc[0][0], 0, 0, 0);
                    acc[0][1] = __builtin_amdgcn_mfma_f32_16x16x32_bf16(a0, b1, acc[0][1], 0, 0, 0);
                    acc[1][0] = __builtin_amdgcn_mfma_f32_16x16x32_bf16(a1, b0, acc[1][0], 0, 0, 0);
                    acc[1][1] = __builtin_amdgcn_mfma_f32_16x16x32_bf16(a1, b1, acc[1][1], 0, 0, 0);
                }
            }
        } else {                       // h region (L2-resident)
            const unsigned short* a0p = hprev + hoff0;
            const unsigned short* a1p = hprev + hoff1;
#pragma unroll 4
            for (int ch = 0; ch < 16; ++ch) {
                short8 a0 = *reinterpret_cast<const short8*>(a0p + ch * 32);
                short8 a1 = *reinterpret_cast<const short8*>(a1p + ch * 32);
                short8 b0 = *reinterpret_cast<const short8*>(bp0 + ch * 32);
                short8 b1 = *reinterpret_cast<const short8*>(bp1 + ch * 32);
                acc[0][0] = __builtin_amdgcn_mfma_f32_16x16x32_bf16(a0, b0, acc[0][0], 0, 0, 0);
                acc[0][1] = __builtin_amdgcn_mfma_f32_16x16x32_bf16(a0, b1, acc[0][1], 0, 0, 0);
                acc[1][0] = __builtin_amdgcn_mfma_f32_16x16x32_bf16(a1, b0, acc[1][0], 0, 0, 0);
                acc[1][1] = __builtin_amdgcn_mfma_f32_16x16x32_bf16(a1, b1, acc[1][1], 0, 0, 0);
            }
        }

        // ---- k-partial reduce in LDS ----
        int r0 = (lane >> 4) << 2;
        if (wk < 2) {
#pragma unroll
            for (int mf = 0; mf < 2; ++mf)
#pragma unroll
                for (int fn = 0; fn < 2; ++fn)
                    *reinterpret_cast<f32x4*>(
                        &red[wk][wn * 32 + fn * 16 + cw][wm * 32 + mf * 16 + r0]) = acc[mf][fn];
        }
        __syncthreads();
        if (wk >= 2) {
#pragma unroll
            for (int mf = 0; mf < 2; ++mf)
#pragma unroll
                for (int fn = 0; fn < 2; ++fn) {
                    float* p = &red[wk - 2][wn * 32 + fn * 16 + cw][wm * 32 + mf * 16 + r0];
                    f32x4 v = *reinterpret_cast<const f32x4*>(p);
                    v += acc[mf][fn];
                    *reinterpret_cast<f32x4*>(p) = v;
                }
        }
        __syncthreads();

        // ---- epilogue: thread = (row er, col ej) ----
        // Issue ALL G loads first (8 x 16B, cached/L3-resident) for MLP.
        u32x4 gv[8];
#pragma unroll
        for (int g = 0; g < 4; ++g) {
            gv[g * 2]     = gbase[g * 1024 * 2];      // (g*HH)*16 bytes /16 = g*1024 u32x4... 
            gv[g * 2 + 1] = gbase[g * 1024 * 2 + 1];
        }

        float sm[16];
        {
            const float4* lp = reinterpret_cast<const float4*>(lgcur + (size_t)en * 16);
            float4 s0 = lp[0], s1 = lp[1], s2 = lp[2], s3 = lp[3];
            float s[16] = {s0.x,s0.y,s0.z,s0.w, s1.x,s1.y,s1.z,s1.w,
                           s2.x,s2.y,s2.z,s2.w, s3.x,s3.y,s3.z,s3.w};
            float mx = -1e30f;
#pragma unroll
            for (int l = 0; l < 16; ++l) { s[l] *= 0.03125f; mx = fmaxf(mx, s[l]); }
            float sum = 0.f;
#pragma unroll
            for (int l = 0; l < 16; ++l) { sm[l] = __expf(s[l] - mx); sum += sm[l]; }
            float inv = 1.f / sum;
#pragma unroll
            for (int l = 0; l < 16; ++l) sm[l] *= inv;
        }

        float pre[4];
#pragma unroll
        for (int g = 0; g < 4; ++g) {
            int colL = g * 16 + ej;
            float p = red[0][colL][er] + red[1][colL][er] + bias[g];
            float d = 0.f;
#pragma unroll
            for (int q = 0; q < 4; ++q) {
                d += sm[q * 2]     * bf2f((unsigned short)(gv[g * 2][q] & 0xFFFF));
                d += sm[q * 2 + 1] * bf2f((unsigned short)(gv[g * 2][q] >> 16));
            }
#pragma unroll
            for (int q = 0; q < 4; ++q) {
                d += sm[8 + q * 2]     * bf2f((unsigned short)(gv[g * 2 + 1][q] & 0xFFFF));
                d += sm[8 + q * 2 + 1] * bf2f((unsigned short)(gv[g * 2 + 1][q] >> 16));
            }
            pre[g] = p + d;
        }

        float cv = c[(size_t)en * HH + ejj];
        float ig = sigm(pre[0]);
        float fg = sigm(pre[1]);
        float og = sigm(pre[2]);
        float gg = tanhf_(pre[3]);
        float cn = fg * cv + ig * gg;
        float hn = og * tanhf_(cn);
        c[(size_t)en * HH + ejj] = cn;
        hnext[(size_t)en * HH + ejj] = f2bf(hn);
        __builtin_nontemporal_store(hn, out + ((size_t)en * TT + t) * HH + ejj);
        hn_s[er][ej] = hn;
        if (zeroer) lgz[(size_t)en * 16 + ej] = 0.f;
        __syncthreads();

        // ---- next-step logit partials via AfT (coalesced 32B reads) ----
        {
            uint4 q0 = *reinterpret_cast<const uint4*>(afp);
            uint4 q1 = *reinterpret_cast<const uint4*>(afp + 8);
            const unsigned* au = reinterpret_cast<const unsigned*>(&q0);
            const unsigned* av = reinterpret_cast<const unsigned*>(&q1);
            float part = 0.f;
#pragma unroll
            for (int q = 0; q < 4; ++q) {
                part += hn_s[er][q * 2]     * bf2f((unsigned short)(au[q] & 0xFFFF));
                part += hn_s[er][q * 2 + 1] * bf2f((unsigned short)(au[q] >> 16));
            }
#pragma unroll
            for (int q = 0; q < 4; ++q) {
                part += hn_s[er][8 + q * 2]     * bf2f((unsigned short)(av[q] & 0xFFFF));
                part += hn_s[er][8 + q * 2 + 1] * bf2f((unsigned short)(av[q] >> 16));
            }
            atomicAdd(&lgnext[(size_t)en * 16 + ej], part);
        }

        grid.sync();
    }
}

// ---------------------------------------------------------------------------
extern "C" void kernel_launch(void* const* d_in, const int* in_sizes, int n_in,
                              void* d_out, int out_size, void* d_ws, size_t ws_size,
                              hipStream_t stream) {
    const float* x     = (const float*)d_in[0];
    const float* A     = (const float*)d_in[1];
    const float* Wx    = (const float*)d_in[2];
    const float* Wh    = (const float*)d_in[3];
    const float* Wattn = (const float*)d_in[4];
    const float* bptr  = (const float*)d_in[5];
    float* out = (float*)d_out;

    char* ws = (char*)d_ws;
    unsigned short* Wt   = (unsigned short*)(ws);              // 25,165,824
    unsigned short* G    = (unsigned short*)(ws + 25165824);   // 33,554,432
    unsigned short* AfT  = (unsigned short*)(ws + 58720256);   //  8,388,608
    unsigned short* hbuf = (unsigned short*)(ws + 67108864);   //  1,048,576 (2 slots)
    float* c             = (float*)(ws + 68157440);            //  1,048,576
    float* lg            = (float*)(ws + 69206016);            //     49,152 (3 bufs)
    unsigned short* xbf  = (unsigned short*)(ws + 69255168);   // 67,108,864 (optional)
    bool use_xbf = ws_size >= (size_t)69255168 + 67108864;

    wt_prep<<<dim3(48, 64), 256, 0, stream>>>(Wx, Wh, Wattn, Wt);
    zero_buf<<<48, 256, 0, stream>>>(lg, 3 * NB * 16);
    afT_prep<<<NB, 256, 0, stream>>>(A, AfT);
    g_gemm<<<dim3(32, 32), 256, 0, stream>>>(AfT, Wt, G);
    init_kernel<<<256, 512, 0, stream>>>(A, c, hbuf, lg);
    if (use_xbf) xconv<<<16384, 256, 0, stream>>>(x, xbf);

    void* args[] = { (void*)&x, (void*)&xbf, (void*)&hbuf, (void*)&Wt, (void*)&G,
                     (void*)&AfT, (void*)&bptr, (void*)&lg, (void*)&c, (void*)&out };
    const void* kfn = use_xbf ? reinterpret_cast<const void*>(&lstm_persist<true>)
                              : reinterpret_cast<const void*>(&lstm_persist<false>);
    (void)hipLaunchCooperativeKernel(kfn, dim3(256), dim3(1024), args, 0, stream);
}

// Round 9
// 4264.379 us; speedup vs baseline: 1.9774x; 1.9774x over previous
//
#include <hip/hip_runtime.h>
#include <hip/hip_bf16.h>

#define NB 256
#define TT 128
#define DD 1024
#define HH 1024
#define FH 4096
#define KTOT 3072

typedef __attribute__((ext_vector_type(4))) float f32x4;
typedef __attribute__((ext_vector_type(8))) short short8;
typedef __attribute__((ext_vector_type(4))) unsigned u32x4;

__device__ __forceinline__ unsigned short f2bf(float f) {
    union { float f; unsigned u; } v; v.f = f;
    unsigned u = v.u;
    u += 0x7FFFu + ((u >> 16) & 1u);   // RNE
    return (unsigned short)(u >> 16);
}
__device__ __forceinline__ float bf2f(unsigned short u) {
    union { unsigned u; float f; } v; v.u = ((unsigned)u) << 16; return v.f;
}
__device__ __forceinline__ float sigm(float v) { return 1.f / (1.f + __expf(-v)); }
__device__ __forceinline__ float tanhf_(float v) { return 1.f - 2.f / (__expf(2.f * v) + 1.f); }

__device__ __forceinline__ void bmap(int bid, int& m0, int& j0) {
    int xx = bid & 7, yy = (bid >> 3) & 7, mt = bid >> 6;
    m0 = mt * 64;
    j0 = (xx * 8 + yy) * 16;           // XCD-aligned j tiles (init kernel)
}

__device__ __forceinline__ short8 pack8(float4 v0, float4 v1) {
    short8 r;
    r[0] = (short)f2bf(v0.x); r[1] = (short)f2bf(v0.y);
    r[2] = (short)f2bf(v0.z); r[3] = (short)f2bf(v0.w);
    r[4] = (short)f2bf(v1.x); r[5] = (short)f2bf(v1.y);
    r[6] = (short)f2bf(v1.z); r[7] = (short)f2bf(v1.w);
    return r;
}

// ---------------------------------------------------------------------------
// Wt[c][k] bf16: c = gate*1024+j (4096), k = concat(x, h, attn-weight rows)
// ---------------------------------------------------------------------------
__global__ __launch_bounds__(256) void wt_prep(const float* __restrict__ Wx,
                                               const float* __restrict__ Wh,
                                               const float* __restrict__ Wattn,
                                               unsigned short* __restrict__ Wt) {
    __shared__ unsigned short tile[64][65];
    int k0 = blockIdx.x * 64;   // 48
    int c0 = blockIdx.y * 64;   // 64
    const float* src; int kl0;
    if (k0 < 1024)      { src = Wx;    kl0 = k0; }
    else if (k0 < 2048) { src = Wh;    kl0 = k0 - 1024; }
    else                { src = Wattn; kl0 = k0 - 2048; }
    int tid = threadIdx.x;
    int r = tid >> 2;
    int ch = (tid & 3) << 4;
    const float* p = src + (size_t)(kl0 + r) * FH + c0 + ch;
#pragma unroll
    for (int i = 0; i < 16; i += 4) {
        float4 v = *reinterpret_cast<const float4*>(p + i);
        tile[r][ch + i + 0] = f2bf(v.x);
        tile[r][ch + i + 1] = f2bf(v.y);
        tile[r][ch + i + 2] = f2bf(v.z);
        tile[r][ch + i + 3] = f2bf(v.w);
    }
    __syncthreads();
    alignas(16) unsigned short vals[16];
#pragma unroll
    for (int i = 0; i < 16; ++i) vals[i] = tile[ch + i][r];
    unsigned short* q = Wt + (size_t)(c0 + r) * KTOT + k0 + ch;
    *reinterpret_cast<uint4*>(q)     = *reinterpret_cast<uint4*>(&vals[0]);
    *reinterpret_cast<uint4*>(q + 8) = *reinterpret_cast<uint4*>(&vals[8]);
}

__global__ __launch_bounds__(256) void zero_buf(float* __restrict__ p, int n) {
    int i = blockIdx.x * 256 + threadIdx.x;
    if (i < n) p[i] = 0.f;
}

// x (fp32) -> xbf (bf16)
__global__ __launch_bounds__(256) void xconv(const float* __restrict__ x,
                                             unsigned short* __restrict__ xbf) {
    size_t i = ((size_t)blockIdx.x * 256 + threadIdx.x) * 8;
    float4 v0 = *reinterpret_cast<const float4*>(x + i);
    float4 v1 = *reinterpret_cast<const float4*>(x + i + 4);
    short8 p = pack8(v0, v1);
    *reinterpret_cast<short8*>(xbf + i) = p;
}

// AfT[n][l][h] = bf16(A[n][h][l])
__global__ __launch_bounds__(256) void afT_prep(const float* __restrict__ A,
                                                unsigned short* __restrict__ AfT) {
    int n = blockIdx.x;
#pragma unroll
    for (int pass = 0; pass < 4; ++pass) {
        int hh = pass * 256 + threadIdx.x;
        const float4* p = reinterpret_cast<const float4*>(A + ((size_t)n * HH + hh) * 16);
        float4 a0 = p[0], a1 = p[1], a2 = p[2], a3 = p[3];
        float av[16] = {a0.x,a0.y,a0.z,a0.w, a1.x,a1.y,a1.z,a1.w,
                        a2.x,a2.y,a2.z,a2.w, a3.x,a3.y,a3.z,a3.w};
#pragma unroll
        for (int l = 0; l < 16; ++l)
            AfT[((size_t)n * 16 + l) * HH + hh] = f2bf(av[l]);
    }
}

// ---------------------------------------------------------------------------
// G[n][c][l] = sum_h Af[n][h][l] * Wattn[h][c]   (one 4096x4096x1024 GEMM)
// ---------------------------------------------------------------------------
__global__ __launch_bounds__(256) void g_gemm(const unsigned short* __restrict__ AfT,
                                              const unsigned short* __restrict__ Wt,
                                              unsigned short* __restrict__ G) {
    int mt = blockIdx.y;
    int ct = blockIdx.x;
    int tid = threadIdx.x;
    int w = tid >> 6, lane = tid & 63;
    int wm = w >> 1, wn = w & 1;
    int cw = lane & 15, k8 = (lane >> 4) << 3;

    const unsigned short* ap[4];
    const unsigned short* bp[4];
#pragma unroll
    for (int mf = 0; mf < 4; ++mf)
        ap[mf] = AfT + (size_t)(mt * 128 + wm * 64 + mf * 16 + cw) * HH + k8;
#pragma unroll
    for (int fn = 0; fn < 4; ++fn)
        bp[fn] = Wt + (size_t)(ct * 128 + wn * 64 + fn * 16 + cw) * KTOT + 2048 + k8;

    f32x4 acc[4][4];
#pragma unroll
    for (int mf = 0; mf < 4; ++mf)
#pragma unroll
        for (int fn = 0; fn < 4; ++fn)
#pragma unroll
            for (int e = 0; e < 4; ++e) acc[mf][fn][e] = 0.f;

#pragma unroll 4
    for (int ch = 0; ch < 32; ++ch) {
        short8 a[4], b[4];
#pragma unroll
        for (int i = 0; i < 4; ++i)
            a[i] = *reinterpret_cast<const short8*>(ap[i] + ch * 32);
#pragma unroll
        for (int i = 0; i < 4; ++i)
            b[i] = *reinterpret_cast<const short8*>(bp[i] + ch * 32);
#pragma unroll
        for (int mf = 0; mf < 4; ++mf)
#pragma unroll
            for (int fn = 0; fn < 4; ++fn)
                acc[mf][fn] = __builtin_amdgcn_mfma_f32_16x16x32_bf16(
                    a[mf], b[fn], acc[mf][fn], 0, 0, 0);
    }

    int l0 = (lane >> 4) << 2;
#pragma unroll
    for (int mf = 0; mf < 4; ++mf) {
        int n = mt * 8 + wm * 4 + mf;
#pragma unroll
        for (int fn = 0; fn < 4; ++fn) {
            int cc = ct * 128 + wn * 64 + fn * 16 + cw;
            unsigned lo = (unsigned)f2bf(acc[mf][fn][0]) | ((unsigned)f2bf(acc[mf][fn][1]) << 16);
            unsigned hi = (unsigned)f2bf(acc[mf][fn][2]) | ((unsigned)f2bf(acc[mf][fn][3]) << 16);
            uint2 val; val.x = lo; val.y = hi;
            *reinterpret_cast<uint2*>(G + ((size_t)n * FH + cc) * 16 + l0) = val;
        }
    }
}

// ---------------------------------------------------------------------------
// init: h0 = c0 = mean(Af[n,h,:]); h0 bf16; logits(h0) -> lg0
// ---------------------------------------------------------------------------
__global__ __launch_bounds__(512) void init_kernel(const float* __restrict__ A,
                                                   float* __restrict__ c,
                                                   unsigned short* __restrict__ h0,
                                                   float* __restrict__ lg0) {
    int m0, j0; bmap(blockIdx.x, m0, j0);
    int tid = threadIdx.x;
    int r = tid >> 3, j2 = (tid & 7) * 2;
    int n = m0 + r;
    float lg[16];
#pragma unroll
    for (int l = 0; l < 16; ++l) lg[l] = 0.f;
#pragma unroll
    for (int e = 0; e < 2; ++e) {
        int j = j0 + j2 + e;
        const float4* p = reinterpret_cast<const float4*>(A + ((size_t)n * HH + j) * 16);
        float4 a0 = p[0], a1 = p[1], a2 = p[2], a3 = p[3];
        float av[16] = {a0.x,a0.y,a0.z,a0.w, a1.x,a1.y,a1.z,a1.w,
                        a2.x,a2.y,a2.z,a2.w, a3.x,a3.y,a3.z,a3.w};
        float s = 0.f;
#pragma unroll
        for (int l = 0; l < 16; ++l) s += av[l];
        float m = s * 0.0625f;
        c[(size_t)n * HH + j] = m;
        h0[(size_t)n * HH + j] = f2bf(m);
#pragma unroll
        for (int l = 0; l < 16; ++l) lg[l] += m * av[l];
    }
#pragma unroll
    for (int l = 0; l < 16; ++l) {
        lg[l] += __shfl_xor(lg[l], 1);
        lg[l] += __shfl_xor(lg[l], 2);
        lg[l] += __shfl_xor(lg[l], 4);
    }
    int l0 = (tid & 7) * 2;
    atomicAdd(&lg0[(size_t)n * 16 + l0],     lg[l0]);
    atomicAdd(&lg0[(size_t)n * 16 + l0 + 1], lg[l0 + 1]);
}

// ---------------------------------------------------------------------------
// Per-step fused kernel (split launches, 1 dispatch/step).
// Grid 512 = 8 m-tiles(32 rows) x 64 j-tiles(16 j, XCD-swizzled), 256 threads.
// 4 waves, k-split 4 (K-slice 512): wave = 32r x 64c(4 gates x 16 j),
// acc[2][4] = 8 MFMA chains, 6 independent loads/chunk. 2 blocks/CU.
// Epilogue: softmax(lgcur) + w.G fold + LSTM + out + AfT logit partials.
// ---------------------------------------------------------------------------
template<bool XBF>
__global__ __launch_bounds__(256, 4)
void gemm_step(const float* __restrict__ x, const unsigned short* __restrict__ xbf,
               const unsigned short* __restrict__ hprev, unsigned short* __restrict__ hnext,
               const unsigned short* __restrict__ Wt, const unsigned short* __restrict__ G,
               const unsigned short* __restrict__ AfT, const float* __restrict__ bb,
               const float* __restrict__ lgcur, float* __restrict__ lgnext,
               float* __restrict__ lgz, float* __restrict__ c,
               float* __restrict__ out, int t) {
    __shared__ float red[2][64][36];   // [k-pair][colL(gate*16+j)][row]
    __shared__ float hn_s[32][16];

    const int bid = blockIdx.x;
    const int jt = (bid & 7) * 8 + ((bid >> 3) & 7);  // 0..63, XCD-aligned
    const int mt = bid >> 6;                           // 0..7
    const int m0 = mt * 32, j0 = jt * 16;
    const int tid = threadIdx.x;
    const int wk = tid >> 6, lane = tid & 63;
    const int cw = lane & 15, k8 = (lane >> 4) << 3;

    const unsigned short* bp[4];
#pragma unroll
    for (int fn = 0; fn < 4; ++fn)
        bp[fn] = Wt + (size_t)(fn * 1024 + j0 + cw) * KTOT + wk * 512 + k8;

    f32x4 acc[2][4];
#pragma unroll
    for (int mf = 0; mf < 2; ++mf)
#pragma unroll
        for (int fn = 0; fn < 4; ++fn)
#pragma unroll
            for (int e = 0; e < 4; ++e) acc[mf][fn][e] = 0.f;

    if (wk < 2) {                      // x region [0,1024)
        if (XBF) {
            const unsigned short* ap[2];
#pragma unroll
            for (int mf = 0; mf < 2; ++mf)
                ap[mf] = xbf + ((size_t)(m0 + mf * 16 + cw) * TT + t) * DD + wk * 512 + k8;
#pragma unroll 4
            for (int ch = 0; ch < 16; ++ch) {
                short8 a[2], b[4];
#pragma unroll
                for (int i = 0; i < 2; ++i)
                    a[i] = *reinterpret_cast<const short8*>(ap[i] + ch * 32);
#pragma unroll
                for (int i = 0; i < 4; ++i)
                    b[i] = *reinterpret_cast<const short8*>(bp[i] + ch * 32);
#pragma unroll
                for (int mf = 0; mf < 2; ++mf)
#pragma unroll
                    for (int fn = 0; fn < 4; ++fn)
                        acc[mf][fn] = __builtin_amdgcn_mfma_f32_16x16x32_bf16(
                            a[mf], b[fn], acc[mf][fn], 0, 0, 0);
            }
        } else {
            const float* ap[2];
#pragma unroll
            for (int mf = 0; mf < 2; ++mf)
                ap[mf] = x + ((size_t)(m0 + mf * 16 + cw) * TT + t) * DD + wk * 512 + k8;
#pragma unroll 2
            for (int ch = 0; ch < 16; ++ch) {
                short8 a[2], b[4];
#pragma unroll
                for (int i = 0; i < 2; ++i) {
                    float4 u0 = *reinterpret_cast<const float4*>(ap[i] + ch * 32);
                    float4 u1 = *reinterpret_cast<const float4*>(ap[i] + ch * 32 + 4);
                    a[i] = pack8(u0, u1);
                }
#pragma unroll
                for (int i = 0; i < 4; ++i)
                    b[i] = *reinterpret_cast<const short8*>(bp[i] + ch * 32);
#pragma unroll
                for (int mf = 0; mf < 2; ++mf)
#pragma unroll
                    for (int fn = 0; fn < 4; ++fn)
                        acc[mf][fn] = __builtin_amdgcn_mfma_f32_16x16x32_bf16(
                            a[mf], b[fn], acc[mf][fn], 0, 0, 0);
            }
        }
    } else {                           // h region [1024,2048), L2-resident
        const unsigned short* ap[2];
#pragma unroll
        for (int mf = 0; mf < 2; ++mf)
            ap[mf] = hprev + (size_t)(m0 + mf * 16 + cw) * HH + (wk - 2) * 512 + k8;
#pragma unroll 4
        for (int ch = 0; ch < 16; ++ch) {
            short8 a[2], b[4];
#pragma unroll
            for (int i = 0; i < 2; ++i)
                a[i] = *reinterpret_cast<const short8*>(ap[i] + ch * 32);
#pragma unroll
            for (int i = 0; i < 4; ++i)
                b[i] = *reinterpret_cast<const short8*>(bp[i] + ch * 32);
#pragma unroll
            for (int mf = 0; mf < 2; ++mf)
#pragma unroll
                for (int fn = 0; fn < 4; ++fn)
                    acc[mf][fn] = __builtin_amdgcn_mfma_f32_16x16x32_bf16(
                        a[mf], b[fn], acc[mf][fn], 0, 0, 0);
        }
    }

    // ---- k-partial reduce: wk0/1 write red[0/1]; wk2/3 add into red[0/1] ----
    const int r0 = (lane >> 4) << 2;
    if (wk < 2) {
#pragma unroll
        for (int mf = 0; mf < 2; ++mf)
#pragma unroll
            for (int fn = 0; fn < 4; ++fn)
                *reinterpret_cast<f32x4*>(&red[wk][fn * 16 + cw][mf * 16 + r0]) = acc[mf][fn];
    }
    __syncthreads();
    if (wk >= 2) {
#pragma unroll
        for (int mf = 0; mf < 2; ++mf)
#pragma unroll
            for (int fn = 0; fn < 4; ++fn) {
                float* p = &red[wk - 2][fn * 16 + cw][mf * 16 + r0];
                f32x4 v = *reinterpret_cast<const f32x4*>(p);
                v += acc[mf][fn];
                *reinterpret_cast<f32x4*>(p) = v;
            }
    }
    __syncthreads();

    // ---- epilogue: 512 (row,j) tasks, 2 per thread ----
    const bool zeroer = (jt == 0);
#pragma unroll
    for (int s = 0; s < 2; ++s) {
        int task = tid + s * 256;
        int er = task >> 4, ej = task & 15;
        int en = m0 + er, ejj = j0 + ej;

        // issue all 8 G loads first (L3-resident, independent)
        const u32x4* gb = reinterpret_cast<const u32x4*>(G + ((size_t)en * FH + ejj) * 16);
        u32x4 gv[8];
#pragma unroll
        for (int g = 0; g < 4; ++g) {
            gv[g * 2]     = gb[g * 2048];
            gv[g * 2 + 1] = gb[g * 2048 + 1];
        }
        float cv = c[(size_t)en * HH + ejj];

        float sm[16];
        {
            const float4* lp = reinterpret_cast<const float4*>(lgcur + (size_t)en * 16);
            float4 s0 = lp[0], s1 = lp[1], s2 = lp[2], s3 = lp[3];
            float sv[16] = {s0.x,s0.y,s0.z,s0.w, s1.x,s1.y,s1.z,s1.w,
                            s2.x,s2.y,s2.z,s2.w, s3.x,s3.y,s3.z,s3.w};
            float mx = -1e30f;
#pragma unroll
            for (int l = 0; l < 16; ++l) { sv[l] *= 0.03125f; mx = fmaxf(mx, sv[l]); }
            float sum = 0.f;
#pragma unroll
            for (int l = 0; l < 16; ++l) { sm[l] = __expf(sv[l] - mx); sum += sm[l]; }
            float inv = 1.f / sum;
#pragma unroll
            for (int l = 0; l < 16; ++l) sm[l] *= inv;
        }

        float pre[4];
#pragma unroll
        for (int g = 0; g < 4; ++g) {
            float p = red[0][g * 16 + ej][er] + red[1][g * 16 + ej][er] + bb[g * HH + ejj];
            float d = 0.f;
#pragma unroll
            for (int q = 0; q < 4; ++q) {
                d += sm[q * 2]     * bf2f((unsigned short)(gv[g * 2][q] & 0xFFFF));
                d += sm[q * 2 + 1] * bf2f((unsigned short)(gv[g * 2][q] >> 16));
            }
#pragma unroll
            for (int q = 0; q < 4; ++q) {
                d += sm[8 + q * 2]     * bf2f((unsigned short)(gv[g * 2 + 1][q] & 0xFFFF));
                d += sm[8 + q * 2 + 1] * bf2f((unsigned short)(gv[g * 2 + 1][q] >> 16));
            }
            pre[g] = p + d;
        }

        float ig = sigm(pre[0]);
        float fg = sigm(pre[1]);
        float og = sigm(pre[2]);
        float gg = tanhf_(pre[3]);
        float cn = fg * cv + ig * gg;
        float hn = og * tanhf_(cn);
        c[(size_t)en * HH + ejj] = cn;
        hnext[(size_t)en * HH + ejj] = f2bf(hn);
        __builtin_nontemporal_store(hn, out + ((size_t)en * TT + t) * HH + ejj);
        hn_s[er][ej] = hn;
        if (zeroer) lgz[(size_t)en * 16 + ej] = 0.f;
    }
    __syncthreads();

    // ---- next-step logit partials via AfT (32B coalesced reads) ----
#pragma unroll
    for (int s = 0; s < 2; ++s) {
        int task = tid + s * 256;
        int er = task >> 4, ej = task & 15;
        int en = m0 + er;
        const unsigned short* afp = AfT + ((size_t)en * 16 + ej) * HH + j0;
        uint4 q0 = *reinterpret_cast<const uint4*>(afp);
        uint4 q1 = *reinterpret_cast<const uint4*>(afp + 8);
        const unsigned* au = reinterpret_cast<const unsigned*>(&q0);
        const unsigned* av = reinterpret_cast<const unsigned*>(&q1);
        float part = 0.f;
#pragma unroll
        for (int q = 0; q < 4; ++q) {
            part += hn_s[er][q * 2]     * bf2f((unsigned short)(au[q] & 0xFFFF));
            part += hn_s[er][q * 2 + 1] * bf2f((unsigned short)(au[q] >> 16));
        }
#pragma unroll
        for (int q = 0; q < 4; ++q) {
            part += hn_s[er][8 + q * 2]     * bf2f((unsigned short)(av[q] & 0xFFFF));
            part += hn_s[er][8 + q * 2 + 1] * bf2f((unsigned short)(av[q] >> 16));
        }
        atomicAdd(&lgnext[(size_t)en * 16 + ej], part);
    }
}

// ---------------------------------------------------------------------------
extern "C" void kernel_launch(void* const* d_in, const int* in_sizes, int n_in,
                              void* d_out, int out_size, void* d_ws, size_t ws_size,
                              hipStream_t stream) {
    const float* x     = (const float*)d_in[0];
    const float* A     = (const float*)d_in[1];
    const float* Wx    = (const float*)d_in[2];
    const float* Wh    = (const float*)d_in[3];
    const float* Wattn = (const float*)d_in[4];
    const float* bptr  = (const float*)d_in[5];
    float* out = (float*)d_out;

    char* ws = (char*)d_ws;
    unsigned short* Wt   = (unsigned short*)(ws);              // 25,165,824
    unsigned short* G    = (unsigned short*)(ws + 25165824);   // 33,554,432
    unsigned short* AfT  = (unsigned short*)(ws + 58720256);   //  8,388,608
    unsigned short* hbuf = (unsigned short*)(ws + 67108864);   //  1,048,576 (2 slots)
    float* c             = (float*)(ws + 68157440);            //  1,048,576
    float* lg            = (float*)(ws + 69206016);            //     49,152 (3 bufs)
    unsigned short* xbf  = (unsigned short*)(ws + 69255168);   // 67,108,864 (optional)
    bool use_xbf = ws_size >= (size_t)69255168 + 67108864;

    wt_prep<<<dim3(48, 64), 256, 0, stream>>>(Wx, Wh, Wattn, Wt);
    zero_buf<<<48, 256, 0, stream>>>(lg, 3 * NB * 16);
    afT_prep<<<NB, 256, 0, stream>>>(A, AfT);
    g_gemm<<<dim3(32, 32), 256, 0, stream>>>(AfT, Wt, G);
    init_kernel<<<256, 512, 0, stream>>>(A, c, hbuf, lg);
    if (use_xbf) xconv<<<16384, 256, 0, stream>>>(x, xbf);

    for (int t = 0; t < TT; ++t) {
        const unsigned short* hp = hbuf + (size_t)(t & 1) * NB * HH;
        unsigned short* hx       = hbuf + (size_t)((t & 1) ^ 1) * NB * HH;
        const float* lgc = lg + (size_t)(t % 3) * NB * 16;
        float* lgn       = lg + (size_t)((t + 1) % 3) * NB * 16;
        float* lgzz      = lg + (size_t)((t + 2) % 3) * NB * 16;
        if (use_xbf)
            gemm_step<true><<<512, 256, 0, stream>>>(x, xbf, hp, hx, Wt, G, AfT, bptr,
                                                     lgc, lgn, lgzz, c, out, t);
        else
            gemm_step<false><<<512, 256, 0, stream>>>(x, xbf, hp, hx, Wt, G, AfT, bptr,
                                                      lgc, lgn, lgzz, c, out, t);
    }
}